// Round 3
// baseline (232.995 us; speedup 1.0000x reference)
//
#include <hip/hip_runtime.h>
#include <cmath>

#define NTOK 32768
#define HDIM 512
#define GVDIM 640
#define VDIM 320
#define DG 128
#define OUT0_SIZE (NTOK * 256)

typedef __attribute__((ext_vector_type(8))) short s16x8;
typedef __attribute__((ext_vector_type(8))) unsigned short u16x8;
typedef __attribute__((ext_vector_type(8))) _Float16 h16x8;
typedef __attribute__((ext_vector_type(4))) float f32x4;

__device__ __forceinline__ unsigned short f2bf(float f) {
    unsigned u = __float_as_uint(f);
    return (unsigned short)((u + 0x7FFFu + ((u >> 16) & 1u)) >> 16);  // RTN
}

// ---------------- hs fp32 -> bf16 (8 elems/thread) ----------------
__global__ __launch_bounds__(256) void k_cvt_hs(const float* __restrict__ hs,
                                                unsigned short* __restrict__ dst) {
    int i = blockIdx.x * 256 + threadIdx.x;          // 2,097,152 threads
    const float4* s = (const float4*)hs + (size_t)i * 2;
    float4 a = s[0], b = s[1];
    u16x8 o;
    o[0] = f2bf(a.x); o[1] = f2bf(a.y); o[2] = f2bf(a.z); o[3] = f2bf(a.w);
    o[4] = f2bf(b.x); o[5] = f2bf(b.y); o[6] = f2bf(b.z); o[7] = f2bf(b.w);
    *((u16x8*)dst + i) = o;
}

// ------- W [512][640] fp32 -> Wt [640][512] bf16 (+ zero histogram) -------
__global__ __launch_bounds__(256) void k_cvt_wt(const float* __restrict__ W,
                                                unsigned short* __restrict__ Wt,
                                                int* __restrict__ hist) {
    int n = blockIdx.x;
    if (threadIdx.x == 0) hist[n] = 0;
#pragma unroll
    for (int k2 = 0; k2 < 2; ++k2) {
        int k = k2 * 256 + threadIdx.x;
        Wt[(size_t)n * 512 + k] = f2bf(W[(size_t)k * 640 + n]);
    }
}

// ---------------- MFMA GEMM: logits = hs_bf16 . Wt^T + bias -> fp16 ------
__global__ __launch_bounds__(256) void k_gemm(
    const unsigned short* __restrict__ A,   // [NTOK][512] bf16
    const unsigned short* __restrict__ Bt,  // [640][512] bf16
    const float* __restrict__ bias,
    _Float16* __restrict__ logits)          // [NTOK][640]
{
    __shared__ short As[128 * 64];
    __shared__ short Bs[128 * 64];

    const int tid  = threadIdx.x;
    const int lane = tid & 63;
    const int wid  = __builtin_amdgcn_readfirstlane(tid >> 6);
    const int mb   = blockIdx.x & 255;
    const int nb   = blockIdx.x >> 8;
    const int tok0 = mb * 128;
    const int col0 = nb * 128;

    const int r8 = lane >> 3;
    const int c8 = lane & 7;
    const int cl = c8 ^ r8;

    const unsigned short* gA = A  + (size_t)(tok0 + wid * 32 + r8) * 512 + cl * 8;
    const unsigned short* gB = Bt + (size_t)(col0 + wid * 32 + r8) * 512 + cl * 8;

    const int quad = lane >> 4;
    const int m16  = lane & 15;
    const int wm   = (wid >> 1) * 64;
    const int wn   = (wid & 1) * 64;

    f32x4 acc[4][4];
#pragma unroll
    for (int mt = 0; mt < 4; ++mt)
#pragma unroll
        for (int nt = 0; nt < 4; ++nt) acc[mt][nt] = (f32x4){0.f, 0.f, 0.f, 0.f};

    for (int kb = 0; kb < 8; ++kb) {
#pragma unroll
        for (int i = 0; i < 4; ++i) {
            __builtin_amdgcn_global_load_lds(
                (__attribute__((address_space(1))) void*)(gA + (size_t)i * 8 * 512 + kb * 64),
                (__attribute__((address_space(3))) void*)(As + (wid * 32 + i * 8) * 64),
                16, 0, 0);
            __builtin_amdgcn_global_load_lds(
                (__attribute__((address_space(1))) void*)(gB + (size_t)i * 8 * 512 + kb * 64),
                (__attribute__((address_space(3))) void*)(Bs + (wid * 32 + i * 8) * 64),
                16, 0, 0);
        }
        __syncthreads();
#pragma unroll
        for (int ks = 0; ks < 2; ++ks) {
            s16x8 af[4], bf[4];
            const int kch = ks * 4 + quad;
#pragma unroll
            for (int t = 0; t < 4; ++t) {
                int arow = wm + t * 16 + m16;
                af[t] = *(const s16x8*)(As + arow * 64 + (kch ^ (arow & 7)) * 8);
                int brow = wn + t * 16 + m16;
                bf[t] = *(const s16x8*)(Bs + brow * 64 + (kch ^ (brow & 7)) * 8);
            }
#pragma unroll
            for (int mt = 0; mt < 4; ++mt)
#pragma unroll
                for (int nt = 0; nt < 4; ++nt)
                    acc[mt][nt] = __builtin_amdgcn_mfma_f32_16x16x32_bf16(
                        af[mt], bf[nt], acc[mt][nt], 0, 0, 0);
        }
        __syncthreads();
    }

    float bv[4];
#pragma unroll
    for (int nt = 0; nt < 4; ++nt) bv[nt] = bias[col0 + wn + nt * 16 + m16];

#pragma unroll
    for (int mt = 0; mt < 4; ++mt) {
#pragma unroll
        for (int r = 0; r < 4; ++r) {
            int token = tok0 + wm + mt * 16 + quad * 4 + r;
            _Float16* dst = logits + (size_t)token * 640 + col0 + wn + m16;
#pragma unroll
            for (int nt = 0; nt < 4; ++nt)
                dst[nt * 16] = (_Float16)(acc[mt][nt][r] + bv[nt]);
        }
    }
}

// ------ fused argmax (+exact fp32 rescore) + codevector gather + hist ------
// 1024 blocks x 32 tokens. Stage 32x640 fp16 logits to LDS (coalesced 16B),
// then each wave handles 16 token-groups from LDS.
__global__ __launch_bounds__(256) void k_argmax_gather(
    const _Float16* __restrict__ logits, const float* __restrict__ hs,
    const float* __restrict__ W, const float* __restrict__ bias,
    const float* __restrict__ cb, float* __restrict__ out,
    int* __restrict__ hist)
{
    __shared__ _Float16 sl[32 * 640];   // 40 KB

    const int tid  = threadIdx.x;
    const int lane = tid & 63;
    const int wid  = tid >> 6;
    const int tok0 = blockIdx.x * 32;

    // ---- stage logits tile (32*640 fp16 = 2560 x 16B chunks) ----
    const h16x8* src = (const h16x8*)(logits + (size_t)tok0 * 640);
    h16x8* dstl = (h16x8*)sl;
#pragma unroll
    for (int i = 0; i < 10; ++i)
        dstl[i * 256 + tid] = src[i * 256 + tid];
    __syncthreads();

    // ---- 16 token-groups per wave ----
    for (int s = 0; s < 16; ++s) {
        const int tg  = wid * 16 + s;
        const int tok = tg >> 1;        // 0..31 within block
        const int grp = tg & 1;

        float v[5];
#pragma unroll
        for (int j = 0; j < 5; ++j)
            v[j] = (float)sl[tok * 640 + grp * 320 + j * 64 + lane];

        float m = fmaxf(fmaxf(fmaxf(v[0], v[1]), fmaxf(v[2], v[3])), v[4]);
#pragma unroll
        for (int off = 32; off >= 1; off >>= 1) m = fmaxf(m, __shfl_xor(m, off));

        const float thr = m - 0.03f;
        unsigned long long mask[5];
        int count = 0;
#pragma unroll
        for (int j = 0; j < 5; ++j) {
            mask[j] = __ballot(v[j] >= thr);
            count += __popcll(mask[j]);
        }

        int besti = -1;
        if (count == 1) {
#pragma unroll
            for (int j = 0; j < 5; ++j)
                if (besti < 0 && mask[j]) besti = j * 64 + (__ffsll(mask[j]) - 1);
        } else {
            float hsr[8];
#pragma unroll
            for (int i = 0; i < 8; ++i)
                hsr[i] = hs[(size_t)(tok0 + tok) * 512 + i * 64 + lane];
            float bestv = -INFINITY;
            for (int j = 0; j < 5; ++j) {
                unsigned long long mk = mask[j];
                while (mk) {
                    int b = __ffsll(mk) - 1; mk &= mk - 1;
                    int gcol = grp * 320 + j * 64 + b;
                    float p = 0.f;
#pragma unroll
                    for (int i = 0; i < 8; ++i)
                        p = fmaf(hsr[i], W[(size_t)(i * 64 + lane) * 640 + gcol], p);
#pragma unroll
                    for (int off = 32; off >= 1; off >>= 1) p += __shfl_xor(p, off);
                    float val = p + bias[gcol];
                    if (val > bestv) { bestv = val; besti = j * 64 + b; }  // first-max
                }
            }
        }

        // ---- fused gather: 128 floats = float2 per lane ----
        float2 cv = ((const float2*)(cb + (size_t)(grp * VDIM + besti) * DG))[lane];
        ((float2*)(out + (size_t)(tok0 + tok) * 256 + grp * 128))[lane] = cv;
        if (lane == 0) atomicAdd(&hist[grp * VDIM + besti], 1);
    }
}

// ---------------- perplexity ----------------
__global__ void k_perplex(const int* __restrict__ hist, float* __restrict__ out)
{
    __shared__ float sh[GVDIM];
    int t = threadIdx.x;
    float p = (float)hist[t] * (1.0f / (float)NTOK);
    sh[t] = p * logf(p + 1e-7f);
    __syncthreads();
    if (t == 0) {
        float s0 = 0.f, s1 = 0.f;
        for (int i = 0; i < VDIM; ++i)  s0 += sh[i];
        for (int i = VDIM; i < GVDIM; ++i) s1 += sh[i];
        out[0] = expf(-s0) + expf(-s1);
    }
}

extern "C" void kernel_launch(void* const* d_in, const int* in_sizes, int n_in,
                              void* d_out, int out_size, void* d_ws, size_t ws_size,
                              hipStream_t stream)
{
    const float* hs   = (const float*)d_in[0];
    const float* W    = (const float*)d_in[1];
    const float* bias = (const float*)d_in[2];
    const float* cb   = (const float*)d_in[3];

    unsigned short* hsb = (unsigned short*)d_ws;          // 16,777,216 bf16
    unsigned short* wt  = hsb + 16777216;                 // 327,680 bf16
    _Float16* logits    = (_Float16*)(wt + 327680);       // 20,971,520 fp16
    int* hist           = (int*)(logits + 20971520);      // 640 int

    float* out  = (float*)d_out;
    float* perp = out + OUT0_SIZE;

    hipLaunchKernelGGL(k_cvt_hs,        dim3(8192),  dim3(256), 0, stream, hs, hsb);
    hipLaunchKernelGGL(k_cvt_wt,        dim3(GVDIM), dim3(256), 0, stream, W, wt, hist);
    hipLaunchKernelGGL(k_gemm,          dim3(1280),  dim3(256), 0, stream, hsb, wt, bias, logits);
    hipLaunchKernelGGL(k_argmax_gather, dim3(1024),  dim3(256), 0, stream,
                       logits, hs, W, bias, cb, out, hist);
    hipLaunchKernelGGL(k_perplex,       dim3(1),     dim3(GVDIM), 0, stream, hist, perp);
}

// Round 4
// 231.894 us; speedup vs baseline: 1.0047x; 1.0047x over previous
//
#include <hip/hip_runtime.h>
#include <cmath>

#define NTOK 32768
#define HDIM 512
#define GVDIM 640
#define VDIM 320
#define DG 128
#define OUT0_SIZE (NTOK * 256)
#define MARGIN 0.02f

typedef __attribute__((ext_vector_type(8))) short s16x8;
typedef __attribute__((ext_vector_type(8))) unsigned short u16x8;
typedef __attribute__((ext_vector_type(8))) _Float16 h16x8;
typedef __attribute__((ext_vector_type(4))) float f32x4;

__device__ __forceinline__ unsigned short f2bf(float f) {
    unsigned u = __float_as_uint(f);
    return (unsigned short)((u + 0x7FFFu + ((u >> 16) & 1u)) >> 16);  // RTN
}

// ---------------- hs fp32 -> bf16 (8 elems/thread) ----------------
__global__ __launch_bounds__(256) void k_cvt_hs(const float* __restrict__ hs,
                                                unsigned short* __restrict__ dst) {
    int i = blockIdx.x * 256 + threadIdx.x;
    const float4* s = (const float4*)hs + (size_t)i * 2;
    float4 a = s[0], b = s[1];
    u16x8 o;
    o[0] = f2bf(a.x); o[1] = f2bf(a.y); o[2] = f2bf(a.z); o[3] = f2bf(a.w);
    o[4] = f2bf(b.x); o[5] = f2bf(b.y); o[6] = f2bf(b.z); o[7] = f2bf(b.w);
    *((u16x8*)dst + i) = o;
}

// ---- W [512][640] fp32 -> Wt [640][512] bf16 (+ zero hist & list ctr) ----
__global__ __launch_bounds__(256) void k_cvt_wt(const float* __restrict__ W,
                                                unsigned short* __restrict__ Wt,
                                                int* __restrict__ hist,
                                                int* __restrict__ ctr) {
    int n = blockIdx.x;
    if (threadIdx.x == 0) hist[n] = 0;
    if (n == 0 && threadIdx.x == 1) ctr[0] = 0;
#pragma unroll
    for (int k2 = 0; k2 < 2; ++k2) {
        int k = k2 * 256 + threadIdx.x;
        Wt[(size_t)n * 512 + k] = f2bf(W[(size_t)k * 640 + n]);
    }
}

// ---------------- MFMA GEMM: logits = hs_bf16 . Wt^T + bias -> fp16 ------
__global__ __launch_bounds__(256) void k_gemm(
    const unsigned short* __restrict__ A,   // [NTOK][512] bf16
    const unsigned short* __restrict__ Bt,  // [640][512] bf16
    const float* __restrict__ bias,
    _Float16* __restrict__ logits)          // [NTOK][640]
{
    __shared__ short As[128 * 64];
    __shared__ short Bs[128 * 64];

    const int tid  = threadIdx.x;
    const int lane = tid & 63;
    const int wid  = __builtin_amdgcn_readfirstlane(tid >> 6);
    const int mb   = blockIdx.x & 255;
    const int nb   = blockIdx.x >> 8;
    const int tok0 = mb * 128;
    const int col0 = nb * 128;

    const int r8 = lane >> 3;
    const int c8 = lane & 7;
    const int cl = c8 ^ r8;

    const unsigned short* gA = A  + (size_t)(tok0 + wid * 32 + r8) * 512 + cl * 8;
    const unsigned short* gB = Bt + (size_t)(col0 + wid * 32 + r8) * 512 + cl * 8;

    const int quad = lane >> 4;
    const int m16  = lane & 15;
    const int wm   = (wid >> 1) * 64;
    const int wn   = (wid & 1) * 64;

    f32x4 acc[4][4];
#pragma unroll
    for (int mt = 0; mt < 4; ++mt)
#pragma unroll
        for (int nt = 0; nt < 4; ++nt) acc[mt][nt] = (f32x4){0.f, 0.f, 0.f, 0.f};

    for (int kb = 0; kb < 8; ++kb) {
#pragma unroll
        for (int i = 0; i < 4; ++i) {
            __builtin_amdgcn_global_load_lds(
                (__attribute__((address_space(1))) void*)(gA + (size_t)i * 8 * 512 + kb * 64),
                (__attribute__((address_space(3))) void*)(As + (wid * 32 + i * 8) * 64),
                16, 0, 0);
            __builtin_amdgcn_global_load_lds(
                (__attribute__((address_space(1))) void*)(gB + (size_t)i * 8 * 512 + kb * 64),
                (__attribute__((address_space(3))) void*)(Bs + (wid * 32 + i * 8) * 64),
                16, 0, 0);
        }
        __syncthreads();
#pragma unroll
        for (int ks = 0; ks < 2; ++ks) {
            s16x8 af[4], bf[4];
            const int kch = ks * 4 + quad;
#pragma unroll
            for (int t = 0; t < 4; ++t) {
                int arow = wm + t * 16 + m16;
                af[t] = *(const s16x8*)(As + arow * 64 + (kch ^ (arow & 7)) * 8);
                int brow = wn + t * 16 + m16;
                bf[t] = *(const s16x8*)(Bs + brow * 64 + (kch ^ (brow & 7)) * 8);
            }
#pragma unroll
            for (int mt = 0; mt < 4; ++mt)
#pragma unroll
                for (int nt = 0; nt < 4; ++nt)
                    acc[mt][nt] = __builtin_amdgcn_mfma_f32_16x16x32_bf16(
                        af[mt], bf[nt], acc[mt][nt], 0, 0, 0);
        }
        __syncthreads();
    }

    float bv[4];
#pragma unroll
    for (int nt = 0; nt < 4; ++nt) bv[nt] = bias[col0 + wn + nt * 16 + m16];

#pragma unroll
    for (int mt = 0; mt < 4; ++mt) {
#pragma unroll
        for (int r = 0; r < 4; ++r) {
            int token = tok0 + wm + mt * 16 + quad * 4 + r;
            _Float16* dst = logits + (size_t)token * 640 + col0 + wn + m16;
#pragma unroll
            for (int nt = 0; nt < 4; ++nt)
                dst[nt * 16] = (_Float16)(acc[mt][nt][r] + bv[nt]);
        }
    }
}

// ---- phase A: per-thread register-resident scan (no shuffles, no LDS) ----
// thread = token-group; 40 x 16B loads; running packed max; branchless scan.
__global__ __launch_bounds__(256, 1) void k_scan(
    const _Float16* __restrict__ logits,
    int* __restrict__ idx_out, int* __restrict__ hist,
    int* __restrict__ ctr, int2* __restrict__ list)
{
    const int tg  = blockIdx.x * 256 + threadIdx.x;   // 65536 threads
    const int tok = tg >> 1;
    const int grp = tg & 1;

    const h16x8* row = (const h16x8*)(logits + (size_t)tok * 640 + grp * 320);
    h16x8 v[40];
#pragma unroll
    for (int j = 0; j < 40; ++j) v[j] = row[j];

    // running packed max (2 chains for ILP)
    h16x8 m0 = v[0], m1 = v[1];
#pragma unroll
    for (int j = 2; j < 40; j += 2) {
        m0 = __builtin_elementwise_max(m0, v[j]);
        m1 = __builtin_elementwise_max(m1, v[j + 1]);
    }
    m0 = __builtin_elementwise_max(m0, m1);
    float M = (float)m0[0];
#pragma unroll
    for (int h = 1; h < 8; ++h) M = fmaxf(M, (float)m0[h]);

    const float thr = M - MARGIN;
    int first = -1, cnt = 0;
#pragma unroll
    for (int j = 0; j < 40; ++j) {
#pragma unroll
        for (int h = 0; h < 8; ++h) {
            float f = (float)v[j][h];
            if (f >= thr) { if (first < 0) first = j * 8 + h; ++cnt; }
        }
    }

    if (cnt == 1) {
        idx_out[tg] = first;
        atomicAdd(&hist[grp * VDIM + first], 1);
    } else {
        int p = atomicAdd(ctr, 1);
        list[p] = make_int2(tg, __float_as_int(thr));
    }
}

// ---- phase B: exact fp32 rescore of flagged token-groups (wave each) ----
__global__ __launch_bounds__(256) void k_rescore(
    const _Float16* __restrict__ logits, const float* __restrict__ hs,
    const float* __restrict__ W, const float* __restrict__ bias,
    const int2* __restrict__ list, const int* __restrict__ ctr,
    int* __restrict__ idx_out, int* __restrict__ hist)
{
    const int lane  = threadIdx.x & 63;
    const int wslot = blockIdx.x * 4 + (threadIdx.x >> 6);
    const int n = ctr[0];

    for (int it = wslot; it < n; it += 4096) {
        const int2 rec = list[it];
        const int tok = rec.x >> 1;
        const int grp = rec.x & 1;
        const float thr = __int_as_float(rec.y);

        const _Float16* lp = logits + (size_t)tok * 640 + grp * 320;
        float hsr[8];
#pragma unroll
        for (int i = 0; i < 8; ++i) hsr[i] = hs[(size_t)tok * 512 + i * 64 + lane];

        float bestv = -INFINITY;
        int   besti = 0;
#pragma unroll
        for (int j = 0; j < 5; ++j) {
            float vv = (float)lp[j * 64 + lane];
            unsigned long long mk = __ballot(vv >= thr);
            while (mk) {
                int b = __ffsll(mk) - 1; mk &= mk - 1;
                int col  = j * 64 + b;
                int gcol = grp * VDIM + col;
                float p = 0.f;
#pragma unroll
                for (int i = 0; i < 8; ++i)
                    p = fmaf(hsr[i], W[(size_t)(i * 64 + lane) * 640 + gcol], p);
#pragma unroll
                for (int off = 32; off >= 1; off >>= 1) p += __shfl_xor(p, off);
                float val = p + bias[gcol];
                if (val > bestv) { bestv = val; besti = col; }  // first-max
            }
        }
        if (lane == 0) {
            idx_out[rec.x] = besti;
            atomicAdd(&hist[grp * VDIM + besti], 1);
        }
    }
}

// ---------------- gather codevectors ----------------
__global__ __launch_bounds__(256) void k_gather(
    const float* __restrict__ cb, const int* __restrict__ idx,
    float* __restrict__ out)
{
    int tid  = threadIdx.x;
    int t    = blockIdx.x * 4 + (tid >> 6);
    int lane = tid & 63;
    int g    = lane >> 5;
    int q    = lane & 31;
    int i    = idx[t * 2 + g];
    const float4* src = (const float4*)(cb + (size_t)(g * VDIM + i) * DG);
    float4 v = src[q];
    ((float4*)(out + (size_t)t * 256))[g * 32 + q] = v;
}

// ---------------- perplexity ----------------
__global__ void k_perplex(const int* __restrict__ hist, float* __restrict__ out)
{
    __shared__ float sh[GVDIM];
    int t = threadIdx.x;
    float p = (float)hist[t] * (1.0f / (float)NTOK);
    sh[t] = p * logf(p + 1e-7f);
    __syncthreads();
    if (t == 0) {
        float s0 = 0.f, s1 = 0.f;
        for (int i = 0; i < VDIM; ++i)  s0 += sh[i];
        for (int i = VDIM; i < GVDIM; ++i) s1 += sh[i];
        out[0] = expf(-s0) + expf(-s1);
    }
}

extern "C" void kernel_launch(void* const* d_in, const int* in_sizes, int n_in,
                              void* d_out, int out_size, void* d_ws, size_t ws_size,
                              hipStream_t stream)
{
    const float* hs   = (const float*)d_in[0];
    const float* W    = (const float*)d_in[1];
    const float* bias = (const float*)d_in[2];
    const float* cb   = (const float*)d_in[3];

    unsigned short* hsb = (unsigned short*)d_ws;          // 16,777,216 bf16
    unsigned short* wt  = hsb + 16777216;                 // 327,680 bf16
    _Float16* logits    = (_Float16*)(wt + 327680);       // 20,971,520 fp16
    int* idx            = (int*)(logits + 20971520);      // 65,536 int
    int* hist           = idx + 65536;                    // 640 int
    int* ctr            = hist + GVDIM;                   // 1 int (+1 pad)
    int2* list          = (int2*)(ctr + 2);               // up to 65,536 int2

    float* out  = (float*)d_out;
    float* perp = out + OUT0_SIZE;

    hipLaunchKernelGGL(k_cvt_hs,  dim3(8192),  dim3(256), 0, stream, hs, hsb);
    hipLaunchKernelGGL(k_cvt_wt,  dim3(GVDIM), dim3(256), 0, stream, W, wt, hist, ctr);
    hipLaunchKernelGGL(k_gemm,    dim3(1280),  dim3(256), 0, stream, hsb, wt, bias, logits);
    hipLaunchKernelGGL(k_scan,    dim3(256),   dim3(256), 0, stream,
                       logits, idx, hist, ctr, list);
    hipLaunchKernelGGL(k_rescore, dim3(1024),  dim3(256), 0, stream,
                       logits, hs, W, bias, list, ctr, idx, hist);
    hipLaunchKernelGGL(k_gather,  dim3(8192),  dim3(256), 0, stream, cb, idx, out);
    hipLaunchKernelGGL(k_perplex, dim3(1),     dim3(GVDIM), 0, stream, hist, perp);
}